// Round 3
// baseline (907.477 us; speedup 1.0000x reference)
//
#include <hip/hip_runtime.h>
#include <math.h>

#define T_TOK 8192
#define DIM   7168
#define NE    256
#define NGRP  8
#define TOPKN 8
#define ROUTE_SCALE 2.5f

#define BM 64
#define BN 64
#define BK 64
#define LDA 68  // padded leading dim for As

static_assert(T_TOK % BM == 0 && NE % BN == 0 && DIM % BK == 0, "tiling");

// ---- scores[t][e] = sigmoid(x[t]·w[e]) + bias[e], fp64 accumulation --------
// (unchanged from round 2 — known-exact logits; isolates the selector change)
__global__ __launch_bounds__(256) void gemm_sigmoid_bias_f64(
    const float* __restrict__ x, const float* __restrict__ w,
    const float* __restrict__ bias, float* __restrict__ scores) {
  __shared__ float As[BM * LDA];   // [m][k], padded
  __shared__ float Bs[BK * BN];    // [k][n] (store-transposed)
  const int tid = threadIdx.x;
  const int m0 = blockIdx.x * BM;
  const int n0 = blockIdx.y * BN;
  const int lr = tid >> 2;         // 0..63: row (token or expert) for loading
  const int lc = (tid & 3) * 16;   // k offset within tile: 0,16,32,48
  const int tx = tid & 15;         // n quad
  const int ty = tid >> 4;         // m quad

  double acc[4][4];
#pragma unroll
  for (int i = 0; i < 4; ++i)
#pragma unroll
    for (int j = 0; j < 4; ++j) acc[i][j] = 0.0;

  for (int kt = 0; kt < DIM; kt += BK) {
#pragma unroll
    for (int r = 0; r < 4; ++r) {
      const float4 v = *reinterpret_cast<const float4*>(
          &x[(size_t)(m0 + lr) * DIM + kt + lc + r * 4]);
      *reinterpret_cast<float4*>(&As[lr * LDA + lc + r * 4]) = v;
    }
#pragma unroll
    for (int r = 0; r < 4; ++r) {
      const float4 v = *reinterpret_cast<const float4*>(
          &w[(size_t)(n0 + lr) * DIM + kt + lc + r * 4]);
      Bs[(lc + r * 4 + 0) * BN + lr] = v.x;
      Bs[(lc + r * 4 + 1) * BN + lr] = v.y;
      Bs[(lc + r * 4 + 2) * BN + lr] = v.z;
      Bs[(lc + r * 4 + 3) * BN + lr] = v.w;
    }
    __syncthreads();

#pragma unroll 4
    for (int k4 = 0; k4 < BK / 4; ++k4) {
      float4 a[4], b[4];
#pragma unroll
      for (int i = 0; i < 4; ++i)
        a[i] = *reinterpret_cast<const float4*>(&As[(ty * 4 + i) * LDA + k4 * 4]);
#pragma unroll
      for (int kk = 0; kk < 4; ++kk)
        b[kk] = *reinterpret_cast<const float4*>(&Bs[(k4 * 4 + kk) * BN + tx * 4]);
#pragma unroll
      for (int kk = 0; kk < 4; ++kk) {
        const double b0 = (double)b[kk].x, b1 = (double)b[kk].y;
        const double b2 = (double)b[kk].z, b3 = (double)b[kk].w;
#pragma unroll
        for (int i = 0; i < 4; ++i) {
          const float af = kk == 0 ? a[i].x : kk == 1 ? a[i].y : kk == 2 ? a[i].z : a[i].w;
          const double av = (double)af;
          acc[i][0] = fma(av, b0, acc[i][0]);
          acc[i][1] = fma(av, b1, acc[i][1]);
          acc[i][2] = fma(av, b2, acc[i][2]);
          acc[i][3] = fma(av, b3, acc[i][3]);
        }
      }
    }
    __syncthreads();
  }

  const float b0 = bias[n0 + tx * 4 + 0];
  const float b1 = bias[n0 + tx * 4 + 1];
  const float b2 = bias[n0 + tx * 4 + 2];
  const float b3 = bias[n0 + tx * 4 + 3];
#pragma unroll
  for (int i = 0; i < 4; ++i) {
    float4 o;
    const float l0 = (float)acc[i][0], l1 = (float)acc[i][1];
    const float l2 = (float)acc[i][2], l3 = (float)acc[i][3];
    o.x = 1.f / (1.f + expf(-l0)) + b0;
    o.y = 1.f / (1.f + expf(-l1)) + b1;
    o.z = 1.f / (1.f + expf(-l2)) + b2;
    o.w = 1.f / (1.f + expf(-l3)) + b3;
    *reinterpret_cast<float4*>(
        &scores[(size_t)(m0 + ty * 4 + i) * NE + n0 + tx * 4]) = o;
  }
}

// ---- serial, literal transcription of the reference selection --------------
// One thread per token. No shuffles. Mirrors jax.lax.top_k stable semantics
// (descending value, ties -> ascending index) via strict-> argmax passes.
__global__ __launch_bounds__(256) void select_topk_serial(
    const float* __restrict__ scores, float* __restrict__ out) {
  const int t = blockIdx.x * blockDim.x + threadIdx.x;
  if (t >= T_TOK) return;
  const float* s = scores + (size_t)t * NE;
  const float NEG_INF = -__builtin_inff();

  // group scores: top-2 sum within each group of 32
  float gs[NGRP];
#pragma unroll
  for (int g = 0; g < NGRP; ++g) {
    float v1 = NEG_INF;
    int i1 = -1;
    for (int i = 0; i < 32; ++i) {
      const float v = s[g * 32 + i];
      if (v > v1) { v1 = v; i1 = i; }
    }
    float v2 = NEG_INF;
    for (int i = 0; i < 32; ++i) {
      if (i == i1) continue;
      const float v = s[g * 32 + i];
      if (v > v2) v2 = v;
    }
    gs[g] = v1 + v2;
  }

  // top-4 groups (strict > keeps lowest index on ties)
  unsigned selmask = 0;
  for (int r = 0; r < 4; ++r) {
    float best = NEG_INF;
    int bg = 0;
    for (int g = 0; g < NGRP; ++g)
      if (!((selmask >> g) & 1u) && gs[g] > best) { best = gs[g]; bg = g; }
    selmask |= (1u << bg);
  }

  // masked scores: sg * mask (0.0 outside selected groups)
  float m[NE];
  for (int e = 0; e < NE; ++e)
    m[e] = ((selmask >> (e >> 5)) & 1u) ? s[e] : 0.0f;

  // top-8 experts over masked, weights gathered from unmasked biased scores
  for (int r = 0; r < TOPKN; ++r) {
    float best = NEG_INF;
    int be = 0;
    for (int e = 0; e < NE; ++e)
      if (m[e] > best) { best = m[e]; be = e; }
    out[(size_t)t * TOPKN + r] = s[be] * ROUTE_SCALE;
    out[(size_t)T_TOK * TOPKN + (size_t)t * TOPKN + r] = (float)be;
    m[be] = NEG_INF;
  }
}

extern "C" void kernel_launch(void* const* d_in, const int* in_sizes, int n_in,
                              void* d_out, int out_size, void* d_ws, size_t ws_size,
                              hipStream_t stream) {
  const float* x = (const float*)d_in[0];
  const float* w = (const float*)d_in[1];
  const float* bias = (const float*)d_in[2];
  float* out = (float*)d_out;

  float* scores = (float*)d_ws;  // 8192*256 f32 = 8 MB

  dim3 gg(T_TOK / BM, NE / BN);
  gemm_sigmoid_bias_f64<<<gg, 256, 0, stream>>>(x, w, bias, scores);

  select_topk_serial<<<(T_TOK + 255) / 256, 256, 0, stream>>>(scores, out);
}

// Round 4
// 288.187 us; speedup vs baseline: 3.1489x; 3.1489x over previous
//
#include <hip/hip_runtime.h>
#include <math.h>
#include <stdint.h>

#define T_TOK 8192
#define DIM   7168
#define NE    256
#define NGRP  8
#define TOPKN 8
#define ROUTE_SCALE 2.5f

// GEMM tiling: 256 threads = 4 waves (2m x 2n), wave tile 32x64, 32x32x16 MFMA
#define BM 64
#define BN 128
#define BK 32
#define LDSBUF (24 * 1024)  // Ah 4KB | Al 4KB | Bh 8KB | Bl 8KB

typedef __bf16 bf16x8 __attribute__((ext_vector_type(8)));
typedef float f32x16 __attribute__((ext_vector_type(16)));

static __device__ __forceinline__ uint16_t f2bf_rne(float f) {
  uint32_t u = __builtin_bit_cast(uint32_t, f);
  u = u + 0x7fffu + ((u >> 16) & 1u);
  return (uint16_t)(u >> 16);
}
static __device__ __forceinline__ float bf2f(uint16_t h) {
  uint32_t u = ((uint32_t)h) << 16;
  return __builtin_bit_cast(float, u);
}
static __device__ __forceinline__ void glds16(const void* g, void* l) {
  __builtin_amdgcn_global_load_lds(
      (const __attribute__((address_space(1))) uint32_t*)g,
      (__attribute__((address_space(3))) uint32_t*)l, 16, 0, 0);
}
static __device__ __forceinline__ bf16x8 ld_frag(const uint8_t* p) {
  return __builtin_bit_cast(bf16x8, *reinterpret_cast<const uint4*>(p));
}

// ---- w [E][D] f32 -> wh/wl bf16, pre-swizzled: granule g' holds source
// granule (g'&~3)|((g'&3)^(e&3))  (16B granules, XOR within 64B blocks) ----
__global__ __launch_bounds__(256) void w_convert(const float* __restrict__ w,
                                                 uint16_t* __restrict__ wh,
                                                 uint16_t* __restrict__ wl) {
  const int e = blockIdx.x;
  const int t = threadIdx.x;
#pragma unroll
  for (int p = 0; p < 4; ++p) {
    const int gp = t + p * 256;
    if (gp >= DIM / 8) break;                       // 896 granules/row
    const int gs = (gp & ~3) | ((gp & 3) ^ (e & 3));
    const float4 a = *reinterpret_cast<const float4*>(&w[(size_t)e * DIM + gs * 8]);
    const float4 b = *reinterpret_cast<const float4*>(&w[(size_t)e * DIM + gs * 8 + 4]);
    const float src[8] = {a.x, a.y, a.z, a.w, b.x, b.y, b.z, b.w};
    uint16_t hs[8], ls[8];
#pragma unroll
    for (int j = 0; j < 8; ++j) {
      const uint16_t h = f2bf_rne(src[j]);
      hs[j] = h;
      ls[j] = f2bf_rne(src[j] - bf2f(h));
    }
    *reinterpret_cast<uint4*>(&wh[(size_t)e * DIM + gp * 8]) =
        *reinterpret_cast<const uint4*>(hs);
    *reinterpret_cast<uint4*>(&wl[(size_t)e * DIM + gp * 8]) =
        *reinterpret_cast<const uint4*>(ls);
  }
}

// ---- split-bf16 3-product MFMA GEMM: partial[ks][t][e] = x[t]·w[e] over its
// K-half. A (x) reg-staged with in-kernel f32->hi/lo cvt; B via global_load_lds
// from pre-swizzled wh/wl. ----
template <int NSPLIT>
__global__ __launch_bounds__(256) void gemm_bf16split(
    const float* __restrict__ x, const uint16_t* __restrict__ wh,
    const uint16_t* __restrict__ wl, float* __restrict__ partial) {
  __shared__ __align__(16) uint8_t lds[2 * LDSBUF];

  const int KH = DIM / NSPLIT;
  const int NIT = KH / BK;
  const int tid = threadIdx.x;
  const int lane = tid & 63;
  const int l31 = lane & 31;
  const int wid = tid >> 6;
  const int wm = wid >> 1, wn = wid & 1;

  // XCD-bijective swizzle; decode so (ks,nblk) pairs sharing x are adjacent
  const int nwg = 128 * 2 * NSPLIT;
  const int q = nwg / 8;
  const int L = (blockIdx.x % 8) * q + blockIdx.x / 8;
  const int per_m = 2 * NSPLIT;
  const int mblk = L / per_m;
  const int rem = L % per_m;
  const int ks = (NSPLIT == 2) ? (rem >> 1) : 0;
  const int nblk = rem & 1;
  const int m0 = mblk * BM, n0 = nblk * BN, k0 = ks * KH;

  // A staging geometry: thread -> row ar (0..63), f32 granules ag, ag+4
  const int ar = tid >> 2;
  const int ag = tid & 3;
  const int ar3 = ar & 3;

  f32x16 acc[2];
#pragma unroll
  for (int nf = 0; nf < 2; ++nf)
#pragma unroll
    for (int r = 0; r < 16; ++r) acc[nf][r] = 0.f;

  auto bStage = [&](uint8_t* dst, const uint16_t* wsw, int kt) {
    const int kg0 = kt >> 3;
#pragma unroll
    for (int r = 0; r < 2; ++r) {
      const int row = r * 64 + (tid >> 2);
      glds16(wsw + (size_t)(n0 + row) * DIM + (size_t)(kg0 + (tid & 3)) * 8,
             dst + r * 4096 + tid * 16);
    }
  };
  auto aLoad = [&](int kt, float4& v1, float4& v2) {
    v1 = *reinterpret_cast<const float4*>(&x[(size_t)(m0 + ar) * DIM + kt + ag * 4]);
    v2 = *reinterpret_cast<const float4*>(&x[(size_t)(m0 + ar) * DIM + kt + (ag + 4) * 4]);
  };
  auto aWrite = [&](uint8_t* buf, const float4& v, int G) {
    const float s[4] = {v.x, v.y, v.z, v.w};
    uint16_t h4[4], l4[4];
#pragma unroll
    for (int j = 0; j < 4; ++j) {
      const uint16_t h = f2bf_rne(s[j]);
      h4[j] = h;
      l4[j] = f2bf_rne(s[j] - bf2f(h));
    }
    const int b = G >> 1, hf = G & 1;
    const int off = ar * 64 + ((b ^ ar3) << 4) + hf * 8;
    *reinterpret_cast<uint2*>(buf + off) = *reinterpret_cast<const uint2*>(h4);         // Ah
    *reinterpret_cast<uint2*>(buf + 4096 + off) = *reinterpret_cast<const uint2*>(l4);  // Al
  };
  auto compute = [&](const uint8_t* buf) {
    const uint8_t* Ah = buf;
    const uint8_t* Al = buf + 4096;
    const uint8_t* Bh = buf + 8192;
    const uint8_t* Bl = buf + 16384;
    const int arow = wm * 32 + l31;
#pragma unroll
    for (int kk = 0; kk < 2; ++kk) {
      const int g = 2 * kk + (lane >> 5);
      const int sg = (g ^ (l31 & 3)) << 4;
      const bf16x8 fAh = ld_frag(Ah + arow * 64 + sg);
      const bf16x8 fAl = ld_frag(Al + arow * 64 + sg);
#pragma unroll
      for (int nf = 0; nf < 2; ++nf) {
        const int brow = wn * 64 + nf * 32 + l31;
        const bf16x8 fBh = ld_frag(Bh + brow * 64 + sg);
        const bf16x8 fBl = ld_frag(Bl + brow * 64 + sg);
        acc[nf] = __builtin_amdgcn_mfma_f32_32x32x16_bf16(fAh, fBh, acc[nf], 0, 0, 0);
        acc[nf] = __builtin_amdgcn_mfma_f32_32x32x16_bf16(fAl, fBh, acc[nf], 0, 0, 0);
        acc[nf] = __builtin_amdgcn_mfma_f32_32x32x16_bf16(fAh, fBl, acc[nf], 0, 0, 0);
      }
    }
  };

  // prologue: stage iter 0 into buf 0
  float4 a1, a2;
  bStage(lds + 8192, wh, k0);
  bStage(lds + 16384, wl, k0);
  aLoad(k0, a1, a2);
  aWrite(lds, a1, ag);
  aWrite(lds, a2, ag + 4);
  __syncthreads();

  int cur = 0;
  for (int it = 0; it < NIT; ++it) {
    const int nxt = cur ^ 1;
    const bool more = (it + 1) < NIT;
    if (more) {
      const int kt = k0 + (it + 1) * BK;
      bStage(lds + nxt * LDSBUF + 8192, wh, kt);
      bStage(lds + nxt * LDSBUF + 16384, wl, kt);
      aLoad(kt, a1, a2);
    }
    compute(lds + cur * LDSBUF);
    if (more) {
      aWrite(lds + nxt * LDSBUF, a1, ag);
      aWrite(lds + nxt * LDSBUF, a2, ag + 4);
    }
    __syncthreads();
    cur = nxt;
  }

  float* pout = partial + (size_t)ks * T_TOK * NE;
#pragma unroll
  for (int nf = 0; nf < 2; ++nf) {
    const int e = n0 + wn * 64 + nf * 32 + l31;
#pragma unroll
    for (int r = 0; r < 16; ++r) {
      const int row = (r & 3) + 8 * (r >> 2) + 4 * (lane >> 5);
      pout[(size_t)(m0 + wm * 32 + row) * NE + e] = acc[nf][r];
    }
  }
}

// ---- scores = sigmoid(p0 (+p1)) + bias; writes overlay p0 ----
__global__ __launch_bounds__(256) void combine_sigmoid_bias(
    const float* __restrict__ p0, const float* __restrict__ p1,
    const float* __restrict__ bias, float* __restrict__ scores, int nsplit) {
  const size_t i4 = (size_t)blockIdx.x * 256 + threadIdx.x;
  float4 v = reinterpret_cast<const float4*>(p0)[i4];
  if (nsplit == 2) {
    const float4 u = reinterpret_cast<const float4*>(p1)[i4];
    v.x += u.x; v.y += u.y; v.z += u.z; v.w += u.w;
  }
  const int e = (int)((i4 * 4) & (NE - 1));
  const float4 bv = *reinterpret_cast<const float4*>(&bias[e]);
  float4 o;
  o.x = 1.f / (1.f + expf(-v.x)) + bv.x;
  o.y = 1.f / (1.f + expf(-v.y)) + bv.y;
  o.z = 1.f / (1.f + expf(-v.z)) + bv.z;
  o.w = 1.f / (1.f + expf(-v.w)) + bv.w;
  reinterpret_cast<float4*>(scores)[i4] = o;
}

// ---- serial, literal transcription of the reference selection (verified) ----
__global__ __launch_bounds__(256) void select_topk_serial(
    const float* __restrict__ scores, float* __restrict__ out) {
  const int t = blockIdx.x * blockDim.x + threadIdx.x;
  if (t >= T_TOK) return;
  const float* s = scores + (size_t)t * NE;
  const float NEG_INF = -__builtin_inff();

  float gs[NGRP];
#pragma unroll
  for (int g = 0; g < NGRP; ++g) {
    float v1 = NEG_INF;
    int i1 = -1;
    for (int i = 0; i < 32; ++i) {
      const float v = s[g * 32 + i];
      if (v > v1) { v1 = v; i1 = i; }
    }
    float v2 = NEG_INF;
    for (int i = 0; i < 32; ++i) {
      if (i == i1) continue;
      const float v = s[g * 32 + i];
      if (v > v2) v2 = v;
    }
    gs[g] = v1 + v2;
  }

  unsigned selmask = 0;
  for (int r = 0; r < 4; ++r) {
    float best = NEG_INF;
    int bg = 0;
    for (int g = 0; g < NGRP; ++g)
      if (!((selmask >> g) & 1u) && gs[g] > best) { best = gs[g]; bg = g; }
    selmask |= (1u << bg);
  }

  float m[NE];
  for (int e = 0; e < NE; ++e)
    m[e] = ((selmask >> (e >> 5)) & 1u) ? s[e] : 0.0f;

  for (int r = 0; r < TOPKN; ++r) {
    float best = NEG_INF;
    int be = 0;
    for (int e = 0; e < NE; ++e)
      if (m[e] > best) { best = m[e]; be = e; }
    out[(size_t)t * TOPKN + r] = s[be] * ROUTE_SCALE;
    out[(size_t)T_TOK * TOPKN + (size_t)t * TOPKN + r] = (float)be;
    m[be] = NEG_INF;
  }
}

extern "C" void kernel_launch(void* const* d_in, const int* in_sizes, int n_in,
                              void* d_out, int out_size, void* d_ws, size_t ws_size,
                              hipStream_t stream) {
  const float* x = (const float*)d_in[0];
  const float* w = (const float*)d_in[1];
  const float* bias = (const float*)d_in[2];
  float* out = (float*)d_out;

  const size_t SC = (size_t)T_TOK * NE * 4;  // 8 MB
  const size_t WB = (size_t)NE * DIM * 2;    // 3.67 MB
  const bool split = ws_size >= 2 * SC + 2 * WB + 1024;

  uint8_t* base = (uint8_t*)d_ws;
  float* p0 = (float*)base;
  uint16_t* whp = (uint16_t*)(base + (split ? 2 * SC : SC));
  uint16_t* wlp = whp + (size_t)NE * DIM;
  const float* p1 = split ? (const float*)(base + SC) : p0;

  w_convert<<<NE, 256, 0, stream>>>(w, whp, wlp);
  if (split)
    gemm_bf16split<2><<<512, 256, 0, stream>>>(x, whp, wlp, p0);
  else
    gemm_bf16split<1><<<256, 256, 0, stream>>>(x, whp, wlp, p0);
  combine_sigmoid_bias<<<2048, 256, 0, stream>>>(p0, p1, bias, p0, split ? 2 : 1);
  select_topk_serial<<<(T_TOK + 255) / 256, 256, 0, stream>>>(p0, out);
}

// Round 5
// 263.265 us; speedup vs baseline: 3.4470x; 1.0947x over previous
//
#include <hip/hip_runtime.h>
#include <math.h>
#include <stdint.h>

#define T_TOK 8192
#define DIM   7168
#define NE    256
#define NGRP  8
#define TOPKN 8
#define ROUTE_SCALE 2.5f

typedef __bf16 bf16x8 __attribute__((ext_vector_type(8)));
typedef float f32x16 __attribute__((ext_vector_type(16)));

static __device__ __forceinline__ uint16_t f2bf_rne(float f) {
  uint32_t u = __builtin_bit_cast(uint32_t, f);
  u = u + 0x7fffu + ((u >> 16) & 1u);
  return (uint16_t)(u >> 16);
}
static __device__ __forceinline__ float bf2f(uint16_t h) {
  uint32_t u = ((uint32_t)h) << 16;
  return __builtin_bit_cast(float, u);
}
static __device__ __forceinline__ bf16x8 ldfrag(const void* p) {
  return __builtin_bit_cast(bf16x8, *reinterpret_cast<const uint4*>(p));
}

// ---- w [E][D] f32 -> wh/wl bf16 (hi + residual-lo), natural layout ---------
__global__ __launch_bounds__(256) void w_convert(const float* __restrict__ w,
                                                 uint16_t* __restrict__ wh,
                                                 uint16_t* __restrict__ wl) {
  const int e = blockIdx.x;
#pragma unroll
  for (int p = 0; p < 4; ++p) {
    const int gp = threadIdx.x + p * 256;  // granule = 8 elems
    if (gp >= DIM / 8) continue;
    const float4 a = *reinterpret_cast<const float4*>(&w[(size_t)e * DIM + gp * 8]);
    const float4 b = *reinterpret_cast<const float4*>(&w[(size_t)e * DIM + gp * 8 + 4]);
    const float src[8] = {a.x, a.y, a.z, a.w, b.x, b.y, b.z, b.w};
    uint16_t hs[8], ls[8];
#pragma unroll
    for (int u = 0; u < 8; ++u) {
      const uint16_t h = f2bf_rne(src[u]);
      hs[u] = h;
      ls[u] = f2bf_rne(src[u] - bf2f(h));
    }
    *reinterpret_cast<uint4*>(&wh[(size_t)e * DIM + gp * 8]) = *reinterpret_cast<const uint4*>(hs);
    *reinterpret_cast<uint4*>(&wl[(size_t)e * DIM + gp * 8]) = *reinterpret_cast<const uint4*>(ls);
  }
}

// ---- split-bf16 3-product MFMA GEMM, B direct from global (L2/L3-resident),
// A reg-staged f32->hi/lo into XOR-swizzled LDS (128B rows, conflict-free).
// Block 128x128, 4 waves (2x2), wave tile 64x64, BK=64, K-split=NSPLIT. ----
template <int NSPLIT>
__global__ __launch_bounds__(256, 2) void gemm_bdirect(
    const float* __restrict__ x, const uint16_t* __restrict__ wh,
    const uint16_t* __restrict__ wl, float* __restrict__ partial) {
  constexpr int NS = 2 * NSPLIT;      // blocks per m-group (2 nblk x NSPLIT ks)
  constexpr int KH = DIM / NSPLIT;
  constexpr int NIT = KH / 64;
  __shared__ __align__(16) uint16_t As[2][2][128][64];  // [buf][hi/lo][row][k]

  const int tid = threadIdx.x;
  const int lane = tid & 63;
  const int l31 = lane & 31;
  const int khalf = lane >> 5;  // which 16B granule of the 32B k-slice
  const int wid = tid >> 6;
  const int wm = wid >> 1, wn = wid & 1;

  // XCD placement: all NS same-m blocks land on one XCD (b%8 == const)
  const int b = blockIdx.x;
  const int xcd = b & 7;
  const int r_ = b >> 3;
  const int ghi = r_ / NS;
  const int j = r_ % NS;
  const int m0 = (ghi * 8 + xcd) * 128;
  const int n0 = (j & 1) * 128;
  const int ks = j >> 1;
  const int k0 = ks * KH;

  const int sr = tid >> 1;  // staging row 0..127
  const int sh = tid & 1;   // staging k-half (32 f32)

  f32x16 acc[2][2];
#pragma unroll
  for (int mf = 0; mf < 2; ++mf)
#pragma unroll
    for (int nf = 0; nf < 2; ++nf)
#pragma unroll
      for (int q = 0; q < 16; ++q) acc[mf][nf][q] = 0.f;

  float4 av[8];
  auto loadA = [&](int kb) {
#pragma unroll
    for (int q = 0; q < 8; ++q)
      av[q] = *reinterpret_cast<const float4*>(
          &x[(size_t)(m0 + sr) * DIM + kb + sh * 32 + q * 4]);
  };
  auto writeA = [&](int buf) {
#pragma unroll
    for (int q2 = 0; q2 < 4; ++q2) {
      uint16_t h8[8], l8[8];
#pragma unroll
      for (int u = 0; u < 8; ++u) {
        const float fv = reinterpret_cast<const float*>(av)[q2 * 8 + u];
        const uint16_t h = f2bf_rne(fv);
        h8[u] = h;
        l8[u] = f2bf_rne(fv - bf2f(h));
      }
      const int G = sh * 4 + q2;
      const int p = G ^ (sr & 7);  // swizzled granule position (128B rows)
      *reinterpret_cast<uint4*>(&As[buf][0][sr][p * 8]) = *reinterpret_cast<const uint4*>(h8);
      *reinterpret_cast<uint4*>(&As[buf][1][sr][p * 8]) = *reinterpret_cast<const uint4*>(l8);
    }
  };

  // prologue
  loadA(k0);
  writeA(0);
  __syncthreads();

  int cur = 0;
  for (int it = 0; it < NIT; ++it) {
    const int kb = k0 + it * 64;
    const bool more = (it + 1) < NIT;

    // issue B loads for this step (16 x 16B/lane, L2/L3-resident)
    bf16x8 Bv[4][2][2];
#pragma unroll
    for (int kk = 0; kk < 4; ++kk)
#pragma unroll
      for (int nf = 0; nf < 2; ++nf) {
        const int er = n0 + wn * 64 + nf * 32 + l31;
        const size_t off = (size_t)er * DIM + kb + (2 * kk + khalf) * 8;
        Bv[kk][nf][0] = ldfrag(wh + off);
        Bv[kk][nf][1] = ldfrag(wl + off);
      }
    // issue next A-tile f32 loads (stay in flight during compute)
    if (more) loadA(kb + 64);

    // compute from LDS buf cur
#pragma unroll
    for (int kk = 0; kk < 4; ++kk) {
      const int G = 2 * kk + khalf;
      bf16x8 fAh[2], fAl[2];
#pragma unroll
      for (int mf = 0; mf < 2; ++mf) {
        const int ar = wm * 64 + mf * 32 + l31;
        const int p = G ^ (ar & 7);
        fAh[mf] = ldfrag(&As[cur][0][ar][p * 8]);
        fAl[mf] = ldfrag(&As[cur][1][ar][p * 8]);
      }
#pragma unroll
      for (int mf = 0; mf < 2; ++mf)
#pragma unroll
        for (int nf = 0; nf < 2; ++nf) {
          acc[mf][nf] = __builtin_amdgcn_mfma_f32_32x32x16_bf16(fAh[mf], Bv[kk][nf][0], acc[mf][nf], 0, 0, 0);
          acc[mf][nf] = __builtin_amdgcn_mfma_f32_32x32x16_bf16(fAl[mf], Bv[kk][nf][0], acc[mf][nf], 0, 0, 0);
          acc[mf][nf] = __builtin_amdgcn_mfma_f32_32x32x16_bf16(fAh[mf], Bv[kk][nf][1], acc[mf][nf], 0, 0, 0);
        }
    }

    if (more) writeA(cur ^ 1);
    __syncthreads();
    cur ^= 1;
  }

  float* pout = partial + (size_t)ks * T_TOK * NE;
#pragma unroll
  for (int mf = 0; mf < 2; ++mf)
#pragma unroll
    for (int nf = 0; nf < 2; ++nf) {
      const int e = n0 + wn * 64 + nf * 32 + l31;
#pragma unroll
      for (int q = 0; q < 16; ++q) {
        const int row = (q & 3) + 8 * (q >> 2) + 4 * khalf;
        pout[(size_t)(m0 + wm * 64 + mf * 32 + row) * NE + e] = acc[mf][nf][q];
      }
    }
}

// ---- combine partials -> scores = sigmoid(sum)+bias; per-group top-2 sums.
// One lane owns one full group of one token (value-only multiset top-2 —
// provably identical to index-exclusion top-2). 32 tokens/block. ----
__global__ __launch_bounds__(256) void combine_gs(
    const float* __restrict__ partial, const float* __restrict__ bias,
    float* __restrict__ scores, float* __restrict__ gs, int nsplit) {
  const int tid = threadIdx.x;
  const int tok = blockIdx.x * 32 + (tid >> 3);
  const int g = tid & 7;
  const size_t rowo = (size_t)tok * NE + g * 32;
  const float NEG_INF = -__builtin_inff();
  float v1 = NEG_INF, v2 = NEG_INF;
#pragma unroll
  for (int c = 0; c < 8; ++c) {
    float4 v = *reinterpret_cast<const float4*>(partial + rowo + c * 4);
    for (int s2 = 1; s2 < nsplit; ++s2) {
      const float4 u = *reinterpret_cast<const float4*>(
          partial + (size_t)s2 * T_TOK * NE + rowo + c * 4);
      v.x += u.x; v.y += u.y; v.z += u.z; v.w += u.w;
    }
    const float4 bv = *reinterpret_cast<const float4*>(bias + g * 32 + c * 4);
    float4 o;
    o.x = 1.f / (1.f + expf(-v.x)) + bv.x;
    o.y = 1.f / (1.f + expf(-v.y)) + bv.y;
    o.z = 1.f / (1.f + expf(-v.z)) + bv.z;
    o.w = 1.f / (1.f + expf(-v.w)) + bv.w;
    const float sv[4] = {o.x, o.y, o.z, o.w};
#pragma unroll
    for (int u = 0; u < 4; ++u) {
      v2 = fmaxf(v2, fminf(v1, sv[u]));
      v1 = fmaxf(v1, sv[u]);
    }
    *reinterpret_cast<float4*>(scores + rowo + c * 4) = o;
  }
  gs[tok * 8 + g] = v1 + v2;
}

// ---- top-4 groups + top-8 experts, exact serial reference semantics,
// scratch-free (8-reg exclusion bitmask, static indexing). 1 thread/token. --
__global__ __launch_bounds__(64) void select_topk2(
    const float* __restrict__ scores, const float* __restrict__ gs,
    float* __restrict__ out) {
  const int t = blockIdx.x * 64 + threadIdx.x;
  const float* s = scores + (size_t)t * NE;
  const float NEG_INF = -__builtin_inff();

  float g8[8];
#pragma unroll
  for (int g = 0; g < 8; ++g) g8[g] = gs[t * 8 + g];

  // top-4 groups (strict >, lowest index on ties — identical to round-3)
  unsigned selmask = 0;
  for (int r = 0; r < 4; ++r) {
    float best = NEG_INF;
    int bg = 0;
#pragma unroll
    for (int g = 0; g < 8; ++g)
      if (!((selmask >> g) & 1u) && g8[g] > best) { best = g8[g]; bg = g; }
    selmask |= (1u << bg);
  }

  // lowest unselected group: source of 0.0-candidates (masked-out entries),
  // consumed in ascending index order; zcnt<=8<32 so it never overflows gz.
  int gz = 0;
#pragma unroll
  for (int g = 7; g >= 0; --g)
    if (!((selmask >> g) & 1u)) gz = g;

  uint32_t excl[8] = {0, 0, 0, 0, 0, 0, 0, 0};
  int zcnt = 0;
  for (int r = 0; r < TOPKN; ++r) {
    float best = NEG_INF;
    int be = -1;
#pragma unroll
    for (int g = 0; g < 8; ++g) {
      if (!((selmask >> g) & 1u)) continue;
      const uint32_t ex = excl[g];
#pragma unroll
      for (int i = 0; i < 32; ++i) {
        const float v = s[g * 32 + i];
        if (!((ex >> i) & 1u) && v > best) { best = v; be = g * 32 + i; }
      }
    }
    const int ze = gz * 32 + zcnt;  // best remaining 0.0-candidate index
    // reference: max value, ties -> lowest index (0.0 entries are real candidates)
    const bool takeReal = (best > 0.0f) || (best == 0.0f && be >= 0 && be < ze);
    int pick;
    if (takeReal) {
      pick = be;
#pragma unroll
      for (int g = 0; g < 8; ++g)
        if ((be >> 5) == g) excl[g] |= 1u << (be & 31);
    } else {
      pick = ze;
      ++zcnt;
    }
    out[(size_t)t * TOPKN + r] = s[pick] * ROUTE_SCALE;  // gather from biased scores
    out[(size_t)T_TOK * TOPKN + (size_t)t * TOPKN + r] = (float)pick;
  }
}

extern "C" void kernel_launch(void* const* d_in, const int* in_sizes, int n_in,
                              void* d_out, int out_size, void* d_ws, size_t ws_size,
                              hipStream_t stream) {
  const float* x = (const float*)d_in[0];
  const float* w = (const float*)d_in[1];
  const float* bias = (const float*)d_in[2];
  float* out = (float*)d_out;

  const size_t SC = (size_t)T_TOK * NE;                       // partial elems
  const size_t WBYTES = (size_t)NE * DIM * 2;                 // one bf16 copy
  const size_t need4 = (4 * SC + (size_t)T_TOK * 8) * 4 + 2 * WBYTES;
  const bool s4 = ws_size >= need4;
  const int nsplit = s4 ? 4 : 2;

  float* part = (float*)d_ws;
  float* gsbuf = part + (size_t)nsplit * SC;
  uint16_t* whp = (uint16_t*)(gsbuf + (size_t)T_TOK * 8);
  uint16_t* wlp = whp + (size_t)NE * DIM;
  float* scores = part;  // overlay partial[0] (read-before-write per element)

  w_convert<<<NE, 256, 0, stream>>>(w, whp, wlp);
  if (s4)
    gemm_bdirect<4><<<64 * 8, 256, 0, stream>>>(x, whp, wlp, part);
  else
    gemm_bdirect<2><<<64 * 4, 256, 0, stream>>>(x, whp, wlp, part);
  combine_gs<<<T_TOK / 32, 256, 0, stream>>>(part, bias, scores, gsbuf, nsplit);
  select_topk2<<<T_TOK / 64, 64, 0, stream>>>(scores, gsbuf, out);
}

// Round 6
// 216.063 us; speedup vs baseline: 4.2001x; 1.2185x over previous
//
#include <hip/hip_runtime.h>
#include <math.h>
#include <stdint.h>

#define T_TOK 8192
#define DIM   7168
#define NE    256
#define NGRP  8
#define TOPKN 8
#define ROUTE_SCALE 2.5f

typedef __bf16 bf16x8 __attribute__((ext_vector_type(8)));
typedef float f32x16 __attribute__((ext_vector_type(16)));

static __device__ __forceinline__ uint16_t f2bf_rne(float f) {
  uint32_t u = __builtin_bit_cast(uint32_t, f);
  u = u + 0x7fffu + ((u >> 16) & 1u);
  return (uint16_t)(u >> 16);
}
static __device__ __forceinline__ float bf2f(uint16_t h) {
  uint32_t u = ((uint32_t)h) << 16;
  return __builtin_bit_cast(float, u);
}
static __device__ __forceinline__ void glds16(const void* g, void* l) {
  __builtin_amdgcn_global_load_lds(
      (const __attribute__((address_space(1))) uint32_t*)g,
      (__attribute__((address_space(3))) uint32_t*)l, 16, 0, 0);
}
static __device__ __forceinline__ bf16x8 ldfrag(const void* p) {
  return __builtin_bit_cast(bf16x8, *reinterpret_cast<const uint4*>(p));
}

// ---- w [E][D] f32 -> wh/wl bf16 (hi + residual-lo), natural layout ---------
__global__ __launch_bounds__(256) void w_convert(const float* __restrict__ w,
                                                 uint16_t* __restrict__ wh,
                                                 uint16_t* __restrict__ wl) {
  const int e = blockIdx.x;
#pragma unroll
  for (int p = 0; p < 4; ++p) {
    const int gp = threadIdx.x + p * 256;  // granule = 8 elems
    if (gp >= DIM / 8) continue;
    const float4 a = *reinterpret_cast<const float4*>(&w[(size_t)e * DIM + gp * 8]);
    const float4 b = *reinterpret_cast<const float4*>(&w[(size_t)e * DIM + gp * 8 + 4]);
    const float src[8] = {a.x, a.y, a.z, a.w, b.x, b.y, b.z, b.w};
    uint16_t hs[8], ls[8];
#pragma unroll
    for (int u = 0; u < 8; ++u) {
      const uint16_t h = f2bf_rne(src[u]);
      hs[u] = h;
      ls[u] = f2bf_rne(src[u] - bf2f(h));
    }
    *reinterpret_cast<uint4*>(&wh[(size_t)e * DIM + gp * 8]) = *reinterpret_cast<const uint4*>(hs);
    *reinterpret_cast<uint4*>(&wl[(size_t)e * DIM + gp * 8]) = *reinterpret_cast<const uint4*>(ls);
  }
}

// ---- split-bf16 3-product MFMA GEMM. 512 thr / 8 waves (2m x 4n), block
// 128x128, BK=64, K-split NSPLIT. B staged hi/lo via global_load_lds (coalesced,
// async, linear LDS dest + XOR-swizzled SOURCE granule); A reg-staged
// f32->hi/lo with same XOR on ds_write. Both double-buffered (128 KB LDS). ----
template <int NSPLIT>
__global__ __launch_bounds__(512, 2) void gemm_split(
    const float* __restrict__ x, const uint16_t* __restrict__ wh,
    const uint16_t* __restrict__ wl, float* __restrict__ partial) {
  constexpr int NS = 2 * NSPLIT;
  constexpr int KH = DIM / NSPLIT;
  constexpr int NIT = KH / 64;
  __shared__ __align__(16) uint16_t As[2][2][128][64];  // [buf][hi/lo][row][k]
  __shared__ __align__(16) uint16_t Bs[2][2][128][64];

  const int tid = threadIdx.x;
  const int lane = tid & 63;
  const int l31 = lane & 31;
  const int khalf = lane >> 5;
  const int wid = tid >> 6;      // 0..7
  const int wm = wid >> 2;       // 0..1
  const int wn = wid & 3;        // 0..3

  // XCD placement: the NS blocks sharing an x m-panel land on one XCD
  const int b = blockIdx.x;
  const int xcd = b & 7;
  const int r_ = b >> 3;
  const int ghi = r_ / NS;
  const int j = r_ % NS;
  const int m0 = (ghi * 8 + xcd) * 128;
  const int n0 = (j & 1) * 128;
  const int ks = j >> 1;
  const int k0 = ks * KH;

  // A staging: 4 threads per row, 16 f32 each
  const int sr = tid >> 2;       // 0..127
  const int sh = tid & 3;        // 16-f32 chunk

  f32x16 acc[2];
#pragma unroll
  for (int mf = 0; mf < 2; ++mf)
#pragma unroll
    for (int q = 0; q < 16; ++q) acc[mf][q] = 0.f;

  float4 av[4];
  auto loadA = [&](int kb) {
#pragma unroll
    for (int q = 0; q < 4; ++q)
      av[q] = *reinterpret_cast<const float4*>(
          &x[(size_t)(m0 + sr) * DIM + kb + sh * 16 + q * 4]);
  };
  auto writeA = [&](int buf) {
#pragma unroll
    for (int g2 = 0; g2 < 2; ++g2) {   // two granules of 8 f32
      uint16_t h8[8], l8[8];
#pragma unroll
      for (int u = 0; u < 8; ++u) {
        const float fv = reinterpret_cast<const float*>(av)[g2 * 8 + u];
        const uint16_t h = f2bf_rne(fv);
        h8[u] = h;
        l8[u] = f2bf_rne(fv - bf2f(h));
      }
      const int G = sh * 2 + g2;
      const int p = G ^ (sr & 7);
      *reinterpret_cast<uint4*>(&As[buf][0][sr][p * 8]) = *reinterpret_cast<const uint4*>(h8);
      *reinterpret_cast<uint4*>(&As[buf][1][sr][p * 8]) = *reinterpret_cast<const uint4*>(l8);
    }
  };
  // B staging via DMA: LDS linear granule g gets source granule (g&7)^(row&7)
  auto stageB = [&](int buf, int kb) {
    const int kg0 = kb >> 3;
#pragma unroll
    for (int half = 0; half < 2; ++half) {
      const int g = tid + half * 512;       // 0..1023
      const int row = g >> 3;
      const int p = g & 7;
      const int srcg = kg0 + (p ^ (row & 7));
      glds16(wh + (size_t)(n0 + row) * DIM + (size_t)srcg * 8,
             &Bs[buf][0][0][0] + (size_t)g * 8);
      glds16(wl + (size_t)(n0 + row) * DIM + (size_t)srcg * 8,
             &Bs[buf][1][0][0] + (size_t)g * 8);
    }
  };
  auto compute = [&](int buf) {
#pragma unroll
    for (int kk = 0; kk < 4; ++kk) {
      const int G = 2 * kk + khalf;
      const int brow = wn * 32 + l31;
      const int pb = G ^ (brow & 7);
      const bf16x8 fBh = ldfrag(&Bs[buf][0][brow][pb * 8]);
      const bf16x8 fBl = ldfrag(&Bs[buf][1][brow][pb * 8]);
#pragma unroll
      for (int mf = 0; mf < 2; ++mf) {
        const int ar = wm * 64 + mf * 32 + l31;
        const int pa = G ^ (ar & 7);
        const bf16x8 fAh = ldfrag(&As[buf][0][ar][pa * 8]);
        const bf16x8 fAl = ldfrag(&As[buf][1][ar][pa * 8]);
        acc[mf] = __builtin_amdgcn_mfma_f32_32x32x16_bf16(fAh, fBh, acc[mf], 0, 0, 0);
        acc[mf] = __builtin_amdgcn_mfma_f32_32x32x16_bf16(fAl, fBh, acc[mf], 0, 0, 0);
        acc[mf] = __builtin_amdgcn_mfma_f32_32x32x16_bf16(fAh, fBl, acc[mf], 0, 0, 0);
      }
    }
  };

  // prologue: fill buffer 0
  loadA(k0);
  stageB(0, k0);
  writeA(0);
  __syncthreads();

  for (int it = 0; it < NIT; ++it) {
    const int kb = k0 + it * 64;
    const int cur = it & 1;
    const int nxt = cur ^ 1;
    const bool more = (it + 1) < NIT;
    if (more) {
      loadA(kb + 64);          // A f32 -> regs, in flight over compute
      stageB(nxt, kb + 64);    // B DMA -> other buffer, in flight over compute
    }
    compute(cur);
    if (more) writeA(nxt);
    __syncthreads();
  }

  float* pout = partial + (size_t)ks * T_TOK * NE;
  const int e = n0 + wn * 32 + l31;
#pragma unroll
  for (int mf = 0; mf < 2; ++mf)
#pragma unroll
    for (int q = 0; q < 16; ++q) {
      const int row = (q & 3) + 8 * (q >> 2) + 4 * khalf;
      pout[(size_t)(m0 + wm * 64 + mf * 32 + row) * NE + e] = acc[mf][q];
    }
}

// ---- combine partials -> scores = sigmoid(sum)+bias; per-group top-2 sums.
// One lane owns one full group of one token. 32 tokens/block. ----
__global__ __launch_bounds__(256) void combine_gs(
    const float* __restrict__ partial, const float* __restrict__ bias,
    float* __restrict__ scores, float* __restrict__ gs, int nsplit) {
  const int tid = threadIdx.x;
  const int tok = blockIdx.x * 32 + (tid >> 3);
  const int g = tid & 7;
  const size_t rowo = (size_t)tok * NE + g * 32;
  const float NEG_INF = -__builtin_inff();
  float v1 = NEG_INF, v2 = NEG_INF;
#pragma unroll
  for (int c = 0; c < 8; ++c) {
    float4 v = *reinterpret_cast<const float4*>(partial + rowo + c * 4);
    for (int s2 = 1; s2 < nsplit; ++s2) {
      const float4 u = *reinterpret_cast<const float4*>(
          partial + (size_t)s2 * T_TOK * NE + rowo + c * 4);
      v.x += u.x; v.y += u.y; v.z += u.z; v.w += u.w;
    }
    const float4 bv = *reinterpret_cast<const float4*>(bias + g * 32 + c * 4);
    float4 o;
    o.x = 1.f / (1.f + expf(-v.x)) + bv.x;
    o.y = 1.f / (1.f + expf(-v.y)) + bv.y;
    o.z = 1.f / (1.f + expf(-v.z)) + bv.z;
    o.w = 1.f / (1.f + expf(-v.w)) + bv.w;
    const float sv[4] = {o.x, o.y, o.z, o.w};
#pragma unroll
    for (int u = 0; u < 4; ++u) {
      v2 = fmaxf(v2, fminf(v1, sv[u]));
      v1 = fmaxf(v1, sv[u]);
    }
    *reinterpret_cast<float4*>(scores + rowo + c * 4) = o;
  }
  gs[tok * 8 + g] = v1 + v2;
}

// ---- top-4 groups + top-8 experts, exact serial reference semantics,
// scratch-free (8-reg exclusion bitmask, static indexing). 1 thread/token. --
__global__ __launch_bounds__(64) void select_topk2(
    const float* __restrict__ scores, const float* __restrict__ gs,
    float* __restrict__ out) {
  const int t = blockIdx.x * 64 + threadIdx.x;
  const float* s = scores + (size_t)t * NE;
  const float NEG_INF = -__builtin_inff();

  float g8[8];
#pragma unroll
  for (int g = 0; g < 8; ++g) g8[g] = gs[t * 8 + g];

  unsigned selmask = 0;
  for (int r = 0; r < 4; ++r) {
    float best = NEG_INF;
    int bg = 0;
#pragma unroll
    for (int g = 0; g < 8; ++g)
      if (!((selmask >> g) & 1u) && g8[g] > best) { best = g8[g]; bg = g; }
    selmask |= (1u << bg);
  }

  int gz = 0;
#pragma unroll
  for (int g = 7; g >= 0; --g)
    if (!((selmask >> g) & 1u)) gz = g;

  uint32_t excl[8] = {0, 0, 0, 0, 0, 0, 0, 0};
  int zcnt = 0;
  for (int r = 0; r < TOPKN; ++r) {
    float best = NEG_INF;
    int be = -1;
#pragma unroll
    for (int g = 0; g < 8; ++g) {
      if (!((selmask >> g) & 1u)) continue;
      const uint32_t ex = excl[g];
#pragma unroll
      for (int i = 0; i < 32; ++i) {
        const float v = s[g * 32 + i];
        if (!((ex >> i) & 1u) && v > best) { best = v; be = g * 32 + i; }
      }
    }
    const int ze = gz * 32 + zcnt;
    const bool takeReal = (best > 0.0f) || (best == 0.0f && be >= 0 && be < ze);
    int pick;
    if (takeReal) {
      pick = be;
#pragma unroll
      for (int g = 0; g < 8; ++g)
        if ((be >> 5) == g) excl[g] |= 1u << (be & 31);
    } else {
      pick = ze;
      ++zcnt;
    }
    out[(size_t)t * TOPKN + r] = s[pick] * ROUTE_SCALE;
    out[(size_t)T_TOK * TOPKN + (size_t)t * TOPKN + r] = (float)pick;
  }
}

extern "C" void kernel_launch(void* const* d_in, const int* in_sizes, int n_in,
                              void* d_out, int out_size, void* d_ws, size_t ws_size,
                              hipStream_t stream) {
  const float* x = (const float*)d_in[0];
  const float* w = (const float*)d_in[1];
  const float* bias = (const float*)d_in[2];
  float* out = (float*)d_out;

  const size_t SC = (size_t)T_TOK * NE;
  const size_t WBYTES = (size_t)NE * DIM * 2;
  const size_t need4 = (4 * SC + (size_t)T_TOK * 8) * 4 + 2 * WBYTES;
  const bool s4 = ws_size >= need4;
  const int nsplit = s4 ? 4 : 2;

  float* part = (float*)d_ws;
  float* gsbuf = part + (size_t)nsplit * SC;
  uint16_t* whp = (uint16_t*)(gsbuf + (size_t)T_TOK * 8);
  uint16_t* wlp = whp + (size_t)NE * DIM;
  float* scores = part;

  w_convert<<<NE, 256, 0, stream>>>(w, whp, wlp);
  if (s4)
    gemm_split<4><<<512, 512, 0, stream>>>(x, whp, wlp, part);
  else
    gemm_split<2><<<256, 512, 0, stream>>>(x, whp, wlp, part);
  combine_gs<<<T_TOK / 32, 256, 0, stream>>>(part, bias, scores, gsbuf, nsplit);
  select_topk2<<<T_TOK / 64, 64, 0, stream>>>(scores, gsbuf, out);
}

// Round 7
// 199.381 us; speedup vs baseline: 4.5515x; 1.0837x over previous
//
#include <hip/hip_runtime.h>
#include <math.h>
#include <stdint.h>

#define T_TOK 8192
#define DIM   7168
#define NE    256
#define NGRP  8
#define TOPKN 8
#define ROUTE_SCALE 2.5f

typedef __bf16 bf16x8 __attribute__((ext_vector_type(8)));
typedef float f32x16 __attribute__((ext_vector_type(16)));

static __device__ __forceinline__ uint16_t f2bf_rne(float f) {
  uint32_t u = __builtin_bit_cast(uint32_t, f);
  u = u + 0x7fffu + ((u >> 16) & 1u);
  return (uint16_t)(u >> 16);
}
static __device__ __forceinline__ float bf2f(uint16_t h) {
  uint32_t u = ((uint32_t)h) << 16;
  return __builtin_bit_cast(float, u);
}
static __device__ __forceinline__ void glds16(const void* g, void* l) {
  __builtin_amdgcn_global_load_lds(
      (const __attribute__((address_space(1))) uint32_t*)g,
      (__attribute__((address_space(3))) uint32_t*)l, 16, 0, 0);
}
static __device__ __forceinline__ bf16x8 ldfrag(const void* p) {
  return __builtin_bit_cast(bf16x8, *reinterpret_cast<const uint4*>(p));
}

// ---- w [E][D] f32 -> wh/wl bf16 (hi + residual-lo), natural layout ---------
__global__ __launch_bounds__(256) void w_convert(const float* __restrict__ w,
                                                 uint16_t* __restrict__ wh,
                                                 uint16_t* __restrict__ wl) {
  const int e = blockIdx.x;
#pragma unroll
  for (int p = 0; p < 4; ++p) {
    const int gp = threadIdx.x + p * 256;  // granule = 8 elems
    if (gp >= DIM / 8) continue;
    const float4 a = *reinterpret_cast<const float4*>(&w[(size_t)e * DIM + gp * 8]);
    const float4 b = *reinterpret_cast<const float4*>(&w[(size_t)e * DIM + gp * 8 + 4]);
    const float src[8] = {a.x, a.y, a.z, a.w, b.x, b.y, b.z, b.w};
    uint16_t hs[8], ls[8];
#pragma unroll
    for (int u = 0; u < 8; ++u) {
      const uint16_t h = f2bf_rne(src[u]);
      hs[u] = h;
      ls[u] = f2bf_rne(src[u] - bf2f(h));
    }
    *reinterpret_cast<uint4*>(&wh[(size_t)e * DIM + gp * 8]) = *reinterpret_cast<const uint4*>(hs);
    *reinterpret_cast<uint4*>(&wl[(size_t)e * DIM + gp * 8]) = *reinterpret_cast<const uint4*>(ls);
  }
}

// ---- split-bf16 3-product MFMA GEMM. Block 128x128, 4 waves (2x2), wave
// tile 64x64, BK=32, K-split NSPLIT. LDS rows = [hi 32 | lo 32] bf16 = 128B
// with p = G^(row&7) XOR swizzle. 64 KB LDS -> 2 blocks/CU (stall overlap).
// XCD-mapped so each XCD holds one (nblk,ks) B-slice (L2-resident). ----
template <int NSPLIT>
__global__ __launch_bounds__(256, 2) void gemm_tile(
    const float* __restrict__ x, const uint16_t* __restrict__ wh,
    const uint16_t* __restrict__ wl, float* __restrict__ partial) {
  constexpr int KH = DIM / NSPLIT;
  constexpr int NIT = KH / 32;
  __shared__ __align__(16) uint16_t As[2][128][64];
  __shared__ __align__(16) uint16_t Bs[2][128][64];

  const int tid = threadIdx.x;
  const int lane = tid & 63;
  const int l31 = lane & 31;
  const int khalf = lane >> 5;
  const int wid = tid >> 6;
  const int wm = wid >> 1, wn = wid & 1;

  const int b = blockIdx.x;
  int mblk, nblk, ks;
  if (NSPLIT == 4) {            // grid 512: b&7 -> (nblk, ks) per XCD
    nblk = b & 1; ks = (b >> 1) & 3; mblk = b >> 3;
  } else {                      // grid 256: b&3 -> (nblk, ks); bit2 -> mblk LSB
    nblk = b & 1; ks = (b >> 1) & 1; mblk = (b >> 3) * 2 + ((b >> 2) & 1);
  }
  const int m0 = mblk * 128, n0 = nblk * 128, k0 = ks * KH;

  const int sr = tid >> 1;      // A staging row 0..127
  const int sh = tid & 1;       // which 16-f32 half of the 32-elem row

  f32x16 acc[2][2];
#pragma unroll
  for (int mf = 0; mf < 2; ++mf)
#pragma unroll
    for (int nf = 0; nf < 2; ++nf)
#pragma unroll
      for (int q = 0; q < 16; ++q) acc[mf][nf][q] = 0.f;

  float4 av[4];
  auto loadA = [&](int kb) {
#pragma unroll
    for (int q = 0; q < 4; ++q)
      av[q] = *reinterpret_cast<const float4*>(
          &x[(size_t)(m0 + sr) * DIM + kb + sh * 16 + q * 4]);
  };
  auto writeA = [&](int buf) {
#pragma unroll
    for (int g2 = 0; g2 < 2; ++g2) {
      uint16_t h8[8], l8[8];
#pragma unroll
      for (int u = 0; u < 8; ++u) {
        const float fv = reinterpret_cast<const float*>(av)[g2 * 8 + u];
        const uint16_t h = f2bf_rne(fv);
        h8[u] = h;
        l8[u] = f2bf_rne(fv - bf2f(h));
      }
      const int G = sh * 2 + g2;          // hi granule 0..3
      const int p = G ^ (sr & 7);
      *reinterpret_cast<uint4*>(&As[buf][sr][p * 8]) = *reinterpret_cast<const uint4*>(h8);
      *reinterpret_cast<uint4*>(&As[buf][sr][(p ^ 4) * 8]) = *reinterpret_cast<const uint4*>(l8);
    }
  };
  // B stage via DMA: LDS granule g (row=g>>3, pos=g&7) <- logical granule
  // G = (g&7)^(row&7); G<4 from wh, else wl. Linear lane-contiguous LDS dest.
  auto stageB = [&](int buf, int kb) {
#pragma unroll
    for (int h = 0; h < 4; ++h) {
      const int g = tid + h * 256;        // 0..1023
      const int row = g >> 3;
      const int G = (g & 7) ^ (row & 7);
      const uint16_t* src = (G < 4)
          ? wh + (size_t)(n0 + row) * DIM + kb + (G & 3) * 8
          : wl + (size_t)(n0 + row) * DIM + kb + (G & 3) * 8;
      glds16(src, &Bs[buf][0][0] + (size_t)g * 8);
    }
  };
  auto compute = [&](int buf) {
#pragma unroll
    for (int kk = 0; kk < 2; ++kk) {
      const int G = kk * 2 + khalf;       // 0..3
      bf16x8 fBh[2], fBl[2], fAh[2], fAl[2];
#pragma unroll
      for (int nf = 0; nf < 2; ++nf) {
        const int brow = wn * 64 + nf * 32 + l31;
        const int pb = G ^ (brow & 7);
        fBh[nf] = ldfrag(&Bs[buf][brow][pb * 8]);
        fBl[nf] = ldfrag(&Bs[buf][brow][(pb ^ 4) * 8]);
      }
#pragma unroll
      for (int mf = 0; mf < 2; ++mf) {
        const int arow = wm * 64 + mf * 32 + l31;
        const int pa = G ^ (arow & 7);
        fAh[mf] = ldfrag(&As[buf][arow][pa * 8]);
        fAl[mf] = ldfrag(&As[buf][arow][(pa ^ 4) * 8]);
      }
#pragma unroll
      for (int mf = 0; mf < 2; ++mf)
#pragma unroll
        for (int nf = 0; nf < 2; ++nf) {
          acc[mf][nf] = __builtin_amdgcn_mfma_f32_32x32x16_bf16(fAh[mf], fBh[nf], acc[mf][nf], 0, 0, 0);
          acc[mf][nf] = __builtin_amdgcn_mfma_f32_32x32x16_bf16(fAl[mf], fBh[nf], acc[mf][nf], 0, 0, 0);
          acc[mf][nf] = __builtin_amdgcn_mfma_f32_32x32x16_bf16(fAh[mf], fBl[nf], acc[mf][nf], 0, 0, 0);
        }
    }
  };

  loadA(k0);
  stageB(0, k0);
  writeA(0);
  __syncthreads();

  for (int it = 0; it < NIT; ++it) {
    const int kb = k0 + it * 32;
    const int cur = it & 1;
    const int nxt = cur ^ 1;
    const bool more = (it + 1) < NIT;
    if (more) {
      loadA(kb + 32);
      stageB(nxt, kb + 32);
    }
    compute(cur);
    if (more) writeA(nxt);
    __syncthreads();
  }

  float* pout = partial + (size_t)ks * T_TOK * NE;
#pragma unroll
  for (int mf = 0; mf < 2; ++mf)
#pragma unroll
    for (int nf = 0; nf < 2; ++nf) {
      const int e = n0 + wn * 64 + nf * 32 + l31;
#pragma unroll
      for (int q = 0; q < 16; ++q) {
        const int row = wm * 64 + mf * 32 + (q & 3) + 8 * (q >> 2) + 4 * khalf;
        pout[(size_t)(m0 + row) * NE + e] = acc[mf][nf][q];
      }
    }
}

// ---- combine partials -> scores = sigmoid(sum)+bias; per-group top-2 sums.
// One lane owns one full group of one token. 32 tokens/block. ----
__global__ __launch_bounds__(256) void combine_gs(
    const float* __restrict__ partial, const float* __restrict__ bias,
    float* __restrict__ scores, float* __restrict__ gs, int nsplit) {
  const int tid = threadIdx.x;
  const int tok = blockIdx.x * 32 + (tid >> 3);
  const int g = tid & 7;
  const size_t rowo = (size_t)tok * NE + g * 32;
  const float NEG_INF = -__builtin_inff();
  float v1 = NEG_INF, v2 = NEG_INF;
#pragma unroll
  for (int c = 0; c < 8; ++c) {
    float4 v = *reinterpret_cast<const float4*>(partial + rowo + c * 4);
    for (int s2 = 1; s2 < nsplit; ++s2) {
      const float4 u = *reinterpret_cast<const float4*>(
          partial + (size_t)s2 * T_TOK * NE + rowo + c * 4);
      v.x += u.x; v.y += u.y; v.z += u.z; v.w += u.w;
    }
    const float4 bv = *reinterpret_cast<const float4*>(bias + g * 32 + c * 4);
    float4 o;
    o.x = 1.f / (1.f + expf(-v.x)) + bv.x;
    o.y = 1.f / (1.f + expf(-v.y)) + bv.y;
    o.z = 1.f / (1.f + expf(-v.z)) + bv.z;
    o.w = 1.f / (1.f + expf(-v.w)) + bv.w;
    const float sv[4] = {o.x, o.y, o.z, o.w};
#pragma unroll
    for (int u = 0; u < 4; ++u) {
      v2 = fmaxf(v2, fminf(v1, sv[u]));
      v1 = fmaxf(v1, sv[u]);
    }
    *reinterpret_cast<float4*>(scores + rowo + c * 4) = o;
  }
  gs[tok * 8 + g] = v1 + v2;
}

// ---- top-4 groups + top-8 experts; exact round-3 serial semantics; the 4
// selected groups' 128 scores cached in registers (fully static indexing). --
__global__ __launch_bounds__(64) void select_topk2(
    const float* __restrict__ scores, const float* __restrict__ gs,
    float* __restrict__ out) {
  const int t = blockIdx.x * 64 + threadIdx.x;
  const float* s = scores + (size_t)t * NE;
  const float NEG_INF = -__builtin_inff();

  float g8[8];
#pragma unroll
  for (int g = 0; g < 8; ++g) g8[g] = gs[t * 8 + g];

  unsigned selmask = 0;
  for (int r = 0; r < 4; ++r) {
    float best = NEG_INF;
    int bg = 0;
#pragma unroll
    for (int g = 0; g < 8; ++g)
      if (!((selmask >> g) & 1u) && g8[g] > best) { best = g8[g]; bg = g; }
    selmask |= (1u << bg);
  }

  // selected groups ascending; lowest unselected group for 0.0-candidates
  unsigned mrem = selmask;
  const int sel0 = __ffs(mrem) - 1; mrem &= mrem - 1;
  const int sel1 = __ffs(mrem) - 1; mrem &= mrem - 1;
  const int sel2 = __ffs(mrem) - 1; mrem &= mrem - 1;
  const int sel3 = __ffs(mrem) - 1;
  const int gz = __ffs(~selmask & 0xffu) - 1;

  // register cache of the 4 selected groups (float4 loads, static indices)
  float ca[4][32];
#pragma unroll
  for (int c = 0; c < 8; ++c) {
    const float4 u0 = *reinterpret_cast<const float4*>(&s[sel0 * 32 + c * 4]);
    const float4 u1 = *reinterpret_cast<const float4*>(&s[sel1 * 32 + c * 4]);
    const float4 u2 = *reinterpret_cast<const float4*>(&s[sel2 * 32 + c * 4]);
    const float4 u3 = *reinterpret_cast<const float4*>(&s[sel3 * 32 + c * 4]);
    ca[0][c * 4 + 0] = u0.x; ca[0][c * 4 + 1] = u0.y; ca[0][c * 4 + 2] = u0.z; ca[0][c * 4 + 3] = u0.w;
    ca[1][c * 4 + 0] = u1.x; ca[1][c * 4 + 1] = u1.y; ca[1][c * 4 + 2] = u1.z; ca[1][c * 4 + 3] = u1.w;
    ca[2][c * 4 + 0] = u2.x; ca[2][c * 4 + 1] = u2.y; ca[2][c * 4 + 2] = u2.z; ca[2][c * 4 + 3] = u2.w;
    ca[3][c * 4 + 0] = u3.x; ca[3][c * 4 + 1] = u3.y; ca[3][c * 4 + 2] = u3.z; ca[3][c * 4 + 3] = u3.w;
  }

  uint32_t ex[4] = {0, 0, 0, 0};
  int zcnt = 0;
  for (int r = 0; r < TOPKN; ++r) {
    float best = NEG_INF;
    int bq = 0, bi = 0;
#pragma unroll
    for (int q = 0; q < 4; ++q)
#pragma unroll
      for (int i = 0; i < 32; ++i) {
        const float v = ca[q][i];
        if (!((ex[q] >> i) & 1u) && v > best) { best = v; bq = q; bi = i; }
      }
    const int bg = (bq == 0) ? sel0 : (bq == 1) ? sel1 : (bq == 2) ? sel2 : sel3;
    const int be = bg * 32 + bi;
    const int ze = gz * 32 + zcnt;  // next 0.0-candidate (ascending index)
    const bool takeReal = (best > 0.0f) || (best == 0.0f && be < ze);
    if (takeReal) {
#pragma unroll
      for (int q = 0; q < 4; ++q)
        if (q == bq) ex[q] |= 1u << bi;
      out[(size_t)t * TOPKN + r] = best * ROUTE_SCALE;
      out[(size_t)T_TOK * TOPKN + (size_t)t * TOPKN + r] = (float)be;
    } else {
      out[(size_t)t * TOPKN + r] = s[ze] * ROUTE_SCALE;
      out[(size_t)T_TOK * TOPKN + (size_t)t * TOPKN + r] = (float)ze;
      ++zcnt;
    }
  }
}

extern "C" void kernel_launch(void* const* d_in, const int* in_sizes, int n_in,
                              void* d_out, int out_size, void* d_ws, size_t ws_size,
                              hipStream_t stream) {
  const float* x = (const float*)d_in[0];
  const float* w = (const float*)d_in[1];
  const float* bias = (const float*)d_in[2];
  float* out = (float*)d_out;

  const size_t SC = (size_t)T_TOK * NE;
  const size_t WBYTES = (size_t)NE * DIM * 2;
  const size_t need4 = (4 * SC + (size_t)T_TOK * 8) * 4 + 2 * WBYTES;
  const bool s4 = ws_size >= need4;
  const int nsplit = s4 ? 4 : 2;

  float* part = (float*)d_ws;
  float* gsbuf = part + (size_t)nsplit * SC;
  uint16_t* whp = (uint16_t*)(gsbuf + (size_t)T_TOK * 8);
  uint16_t* wlp = whp + (size_t)NE * DIM;
  float* scores = part;

  w_convert<<<NE, 256, 0, stream>>>(w, whp, wlp);
  if (s4)
    gemm_tile<4><<<512, 256, 0, stream>>>(x, whp, wlp, part);
  else
    gemm_tile<2><<<256, 256, 0, stream>>>(x, whp, wlp, part);
  combine_gs<<<T_TOK / 32, 256, 0, stream>>>(part, bias, scores, gsbuf, nsplit);
  select_topk2<<<T_TOK / 64, 64, 0, stream>>>(scores, gsbuf, out);
}